// Round 18
// baseline (494.715 us; speedup 1.0000x reference)
//
#include <hip/hip_runtime.h>
#include <cstdint>

#define NBOX 12288
#define NWORDS 192
#define POS_THRESH 0.15f
#define NMS_THRESH 0.7f

typedef unsigned long long u64;
typedef _Float16 half8 __attribute__((ext_vector_type(8)));
typedef float floatx4 __attribute__((ext_vector_type(4)));

// ---------------- Kernel 0a: zero the conv accumulator (fallback path only) ----------------
__global__ __launch_bounds__(256) void zero_y(float4* __restrict__ Y) {
  Y[blockIdx.x * 256 + threadIdx.x] = float4{0.f, 0.f, 0.f, 0.f};
}

// ---------------- Kernel 0b: W (3,3,1024,512) -> WT[tap][n][c] fp16 h/l split ----------------
// l pre-scaled by 4096 so it stays in fp16 normal range.
__global__ __launch_bounds__(256) void prep_wt(
    const float* __restrict__ Wc, _Float16* __restrict__ WTh, _Float16* __restrict__ WTl)
{
  __shared__ float tile[64][65];
  const int b = blockIdx.x;           // 9 taps * 16 c-tiles * 8 n-tiles = 1152
  const int tap = b >> 7;
  const int rem = b & 127;
  const int c0 = (rem >> 3) * 64, n0 = (rem & 7) * 64;
  const int t = threadIdx.x;
  #pragma unroll
  for (int i = 0; i < 16; ++i) {
    const int idx = i * 256 + t;
    const int c = idx >> 6, n = idx & 63;
    tile[n][c] = Wc[((size_t)(tap * 1024 + c0 + c)) * 512 + n0 + n];
  }
  __syncthreads();
  #pragma unroll
  for (int i = 0; i < 16; ++i) {
    const int idx = i * 256 + t;
    const int n = idx >> 6, c = idx & 63;
    const float v = tile[n][c];
    const _Float16 h = (_Float16)v;
    const _Float16 l = (_Float16)((v - (float)h) * 4096.0f);
    const size_t o = ((size_t)(tap * 512 + n0 + n)) * 1024 + c0 + c;
    WTh[o] = h;
    WTl[o] = l;
  }
}

// ---------------- Kernel 1: 3x3 conv via split-fp16 MFMA (v14 = best measured) ----------------
#define AROW 40                 // 32 k-halves padded to 40
#define AS_PLANE (4 * 66 * AROW)
#define BS_PLANE (128 * AROW)
#define YPLANE 2097152          // 4096*512 floats
__global__ __launch_bounds__(256, 2) void conv_mfma(
    const float* __restrict__ X, const _Float16* __restrict__ WTh,
    const _Float16* __restrict__ WTl, float* __restrict__ Y, int partial)
{
  __shared__ _Float16 As[2 * AS_PLANE];   // 42,240 B
  __shared__ _Float16 Bs[2 * BS_PLANE];   // 20,480 B
  const int bid = blockIdx.x;
  const int ks = bid & 3;                 // 4 K-slices of 256 ch
  const int nt = (bid >> 2) & 3;
  const int mt = bid >> 4;
  const int t = threadIdx.x;
  const int lane = t & 63, wid = t >> 6;
  const int wm = wid >> 1, wn = wid & 1;
  const int lrow = lane & 15, quad = lane >> 4;

  floatx4 accH[4][4], accL[4][4];
  #pragma unroll
  for (int i = 0; i < 4; ++i)
    #pragma unroll
    for (int j = 0; j < 4; ++j) { accH[i][j] = (floatx4)0.f; accL[i][j] = (floatx4)0.f; }

  for (int kc = 0; kc < 8; ++kc) {
    const int c0 = ks * 256 + kc * 32;
    __syncthreads();   // prior chunk readers done
    for (int r = t; r < 264; r += 256) {
      const int yy = r / 66;
      const int xx = r - yy * 66;
      const int yi = mt * 2 + yy - 1;
      const int xi = xx - 1;
      const int akey = (r >> 3) & 3;
      _Float16* dsth = &As[r * AROW];
      _Float16* dstl = dsth + AS_PLANE;
      if (yi >= 0 && yi < 64 && xi >= 0 && xi < 64) {
        const float4* src = (const float4*)(X + ((size_t)(yi * 64 + xi)) * 1024 + c0);
        #pragma unroll
        for (int j = 0; j < 4; ++j) {
          const float4 va = src[2 * j], vb = src[2 * j + 1];
          const float f[8] = {va.x, va.y, va.z, va.w, vb.x, vb.y, vb.z, vb.w};
          half8 hh, hl;
          #pragma unroll
          for (int e = 0; e < 8; ++e) {
            const _Float16 h = (_Float16)f[e];
            hh[e] = h;
            hl[e] = (_Float16)((f[e] - (float)h) * 4096.0f);
          }
          const int sl = (j ^ akey) * 8;
          *(half8*)&dsth[sl] = hh;
          *(half8*)&dstl[sl] = hl;
        }
      } else {
        const half8 z = (half8)(_Float16)0.f;
        #pragma unroll
        for (int j = 0; j < 4; ++j) { *(half8*)&dsth[j * 8] = z; *(half8*)&dstl[j * 8] = z; }
      }
    }
    for (int tap = 0; tap < 9; ++tap) {
      if (tap > 0) __syncthreads();   // prior tap's B readers done
      {   // ---- stage B: 256 rows (hl,n) x 32 halves, slot-swizzled ----
        const int hl = t >> 7, n = t & 127;
        const int bkey = (n >> 3) & 3;
        const _Float16* src = (hl ? WTl : WTh) +
            ((size_t)(tap * 512 + nt * 128 + n)) * 1024 + c0;
        _Float16* dst = &Bs[hl * BS_PLANE + n * AROW];
        #pragma unroll
        for (int j = 0; j < 4; ++j)
          *(half8*)&dst[(j ^ bkey) * 8] = *(const half8*)&src[j * 8];
      }
      __syncthreads();   // A (first tap) + B visible
      const int dy = tap / 3 - 1, dx = tap - (tap / 3) * 3 - 1;
      const int yy = wm + dy + 1;
      const int xxb = dx + 1;
      half8 Ah[4], Al[4], Bh[4], Bl[4];
      #pragma unroll
      for (int fm = 0; fm < 4; ++fm) {
        const int row = yy * 66 + xxb + fm * 16 + lrow;
        const int idx = row * AROW + ((quad ^ ((row >> 3) & 3)) * 8);
        Ah[fm] = *(const half8*)&As[idx];
        Al[fm] = *(const half8*)&As[idx + AS_PLANE];
      }
      #pragma unroll
      for (int fn = 0; fn < 4; ++fn) {
        const int row = wn * 64 + fn * 16 + lrow;
        const int idx = row * AROW + ((quad ^ ((row >> 3) & 3)) * 8);
        Bh[fn] = *(const half8*)&Bs[idx];
        Bl[fn] = *(const half8*)&Bs[idx + BS_PLANE];
      }
      #pragma unroll
      for (int fm = 0; fm < 4; ++fm)
        #pragma unroll
        for (int fn = 0; fn < 4; ++fn) {
          accH[fm][fn] = __builtin_amdgcn_mfma_f32_16x16x32_f16(Ah[fm], Bh[fn], accH[fm][fn], 0, 0, 0);
          accL[fm][fn] = __builtin_amdgcn_mfma_f32_16x16x32_f16(Al[fm], Bh[fn], accL[fm][fn], 0, 0, 0);
          accL[fm][fn] = __builtin_amdgcn_mfma_f32_16x16x32_f16(Ah[fm], Bl[fn], accL[fm][fn], 0, 0, 0);
        }
    }
  }
  // ---- epilogue ----
  const int m0 = mt * 128 + wm * 64;
  const int n0 = nt * 128 + wn * 64;
  if (partial) {
    float* Yp = Y + (size_t)ks * YPLANE;
    #pragma unroll
    for (int fm = 0; fm < 4; ++fm)
      #pragma unroll
      for (int fn = 0; fn < 4; ++fn) {
        const int n = n0 + fn * 16 + lrow;
        #pragma unroll
        for (int r = 0; r < 4; ++r) {
          const int m = m0 + fm * 16 + quad * 4 + r;
          Yp[(size_t)m * 512 + n] = accH[fm][fn][r] + accL[fm][fn][r] * (1.0f / 4096.0f);
        }
      }
  } else {
    #pragma unroll
    for (int fm = 0; fm < 4; ++fm)
      #pragma unroll
      for (int fn = 0; fn < 4; ++fn) {
        const int n = n0 + fn * 16 + lrow;
        #pragma unroll
        for (int r = 0; r < 4; ++r) {
          const int m = m0 + fm * 16 + quad * 4 + r;
          atomicAdd(&Y[(size_t)m * 512 + n],
                    accH[fm][fn][r] + accL[fm][fn][r] * (1.0f / 4096.0f));
        }
      }
  }
}

// ---------------- Kernel 2: bias+ReLU + 1x1 heads + softmax(6) + decode + ext init ----------------
__global__ __launch_bounds__(64) void heads_decode(
    const float* __restrict__ Yx, int nparts, const float* __restrict__ Bc,
    const float* __restrict__ Wcls, const float* __restrict__ bcls,
    const float* __restrict__ Wreg, const float* __restrict__ breg,
    float* __restrict__ boxes, float* __restrict__ scores, int* __restrict__ ext)
{
  __shared__ float xs[512];
  const int pos = blockIdx.x;
  const int l = threadIdx.x;
  if (l == 0 && pos < NWORDS) ext[pos] = pos;
  float4 v0 = {0.f, 0.f, 0.f, 0.f};
  float4 v1 = {0.f, 0.f, 0.f, 0.f};
  for (int p = 0; p < nparts; ++p) {
    const float* xrow = Yx + (size_t)p * YPLANE + (size_t)pos * 512;
    const float4 a = *(const float4*)&xrow[l * 8];
    const float4 b = *(const float4*)&xrow[l * 8 + 4];
    v0.x += a.x; v0.y += a.y; v0.z += a.z; v0.w += a.w;
    v1.x += b.x; v1.y += b.y; v1.z += b.z; v1.w += b.w;
  }
  const float4 b0 = *(const float4*)&Bc[l * 8];
  const float4 b1 = *(const float4*)&Bc[l * 8 + 4];
  xs[l * 8 + 0] = fmaxf(v0.x + b0.x, 0.f);
  xs[l * 8 + 1] = fmaxf(v0.y + b0.y, 0.f);
  xs[l * 8 + 2] = fmaxf(v0.z + b0.z, 0.f);
  xs[l * 8 + 3] = fmaxf(v0.w + b0.w, 0.f);
  xs[l * 8 + 4] = fmaxf(v1.x + b1.x, 0.f);
  xs[l * 8 + 5] = fmaxf(v1.y + b1.y, 0.f);
  xs[l * 8 + 6] = fmaxf(v1.z + b1.z, 0.f);
  xs[l * 8 + 7] = fmaxf(v1.w + b1.w, 0.f);
  __syncthreads();

  const float* wp;
  int oc;
  float bini;
  if (l < 6)       { wp = Wcls + l;       oc = 6;  bini = bcls[l]; }
  else if (l < 18) { wp = Wreg + (l - 6); oc = 12; bini = breg[l - 6]; }
  else             { wp = Wcls;           oc = 0;  bini = 0.f; }
  float acc = bini;
  const float* p = wp;
  #pragma unroll 4
  for (int c = 0; c < 512; ++c) { acc = fmaf(xs[c], *p, acc); p += oc; }

  const float l0 = __shfl(acc, 0), l1 = __shfl(acc, 1), l2 = __shfl(acc, 2);
  const float l3 = __shfl(acc, 3), l4 = __shfl(acc, 4), l5 = __shfl(acc, 5);
  const int a = (l < 3) ? l : 0;
  const float d0 = __shfl(acc, 6 + a * 4 + 0);
  const float d1 = __shfl(acc, 6 + a * 4 + 1);
  const float d2 = __shfl(acc, 6 + a * 4 + 2);
  const float d3 = __shfl(acc, 6 + a * 4 + 3);

  const float mx = fmaxf(fmaxf(fmaxf(l0, l1), fmaxf(l2, l3)), fmaxf(l4, l5));
  const float e0 = expf(l0 - mx), e1 = expf(l1 - mx), e2 = expf(l2 - mx);
  const float e3 = expf(l3 - mx), e4 = expf(l4 - mx), e5 = expf(l5 - mx);
  const float den = ((((e0 + e1) + e2) + e3) + e4) + e5;
  const float esel = (a == 0) ? e1 : ((a == 1) ? e3 : e5);
  const float sc = esel / den;

  const int px = pos & 63, py = pos >> 6;
  const float cx = (px + 0.5f) * 16.0f;
  const float cy = (py + 0.5f) * 16.0f;
  const float ratio = (a == 0) ? 0.5f : ((a == 1) ? 1.0f : 2.0f);
  const float sq = sqrtf(ratio);
  const float wsz = 128.0f * sq;
  const float hsz = 128.0f / sq;
  const float a0 = cx - wsz * 0.5f;
  const float a1 = cy - hsz * 0.5f;
  const float a2 = cx + wsz * 0.5f;
  const float a3 = cy + hsz * 0.5f;
  const float w = a2 - a0, h = a3 - a1;
  const float xc = __fadd_rn(__fmul_rn(__fadd_rn(a0, a2), 0.5f), __fmul_rn(d0, w));
  const float yc = __fadd_rn(__fmul_rn(__fadd_rn(a1, a3), 0.5f), __fmul_rn(d1, h));
  const float nw = __fmul_rn(w, expf(d2));
  const float nh = __fmul_rn(h, expf(d3));
  float4 box;
  box.x = __fsub_rn(xc, __fmul_rn(nw, 0.5f));
  box.y = __fsub_rn(yc, __fmul_rn(nh, 0.5f));
  box.z = __fadd_rn(xc, __fmul_rn(nw, 0.5f));
  box.w = __fadd_rn(yc, __fmul_rn(nh, 0.5f));

  if (l < 3) {
    const int idx = pos * 3 + a;
    *(float4*)&boxes[idx * 4] = box;
    scores[idx] = sc;
  }
}

// ---------------- Kernel 3: suppression bit-matrix (column-major) + extent ----------------
__global__ __launch_bounds__(256) void build_mask(
    const float* __restrict__ boxes, u64* __restrict__ maskT,
    int* __restrict__ ext)
{
  const int w  = blockIdx.x;
  const int ci = blockIdx.y;
  if (w < ci) return;
  __shared__ float4 rb[64];
  __shared__ int anyf;
  const int t = threadIdx.x;
  const int lane = t & 63, wid = t >> 6;
  if (t == 0) anyf = 0;
  if (t < 64) rb[t] = *(const float4*)&boxes[(ci * 64 + t) * 4];
  const float4 cb = *(const float4*)&boxes[(w * 64 + lane) * 4];
  const float careaa = __fmul_rn(cb.z - cb.x, cb.w - cb.y);
  const int jglob = w * 64 + lane;
  __syncthreads();
  bool any = false;
  for (int rr = 0; rr < 16; ++rr) {
    const int r = wid * 16 + rr;
    const int row = ci * 64 + r;
    const float4 rx = rb[r];
    const float ra = __fmul_rn(rx.z - rx.x, rx.w - rx.y);
    const float xx1 = fmaxf(rx.x, cb.x);
    const float yy1 = fmaxf(rx.y, cb.y);
    const float xx2 = fminf(rx.z, cb.z);
    const float yy2 = fminf(rx.w, cb.w);
    const float iw = fmaxf(__fsub_rn(xx2, xx1), 0.f);
    const float ih = fmaxf(__fsub_rn(yy2, yy1), 0.f);
    const float inter = __fmul_rn(iw, ih);
    const float den = __fadd_rn(__fsub_rn(__fadd_rn(ra, careaa), inter), 1e-9f);
    const float iou = __fdiv_rn(inter, den);
    const bool bit = (iou > NMS_THRESH) && (jglob > row);
    any |= bit;
    const u64 word = __ballot(bit ? 1 : 0);
    if (lane == 0) maskT[(size_t)w * NBOX + row] = word;
  }
  if (any) anyf = 1;
  __syncthreads();
  if (t == 0 && anyf && w > ci) atomicMax(&ext[ci], w);
}

// ---------------- Kernel 4: NMS, v18: change-gated fixpoint (it-0 forced) + fallback ----
// v17's bug: words with EMPTY windows (lo==w, e.g. word 0) had need=0 at iteration 0
// and never got their in-word greedy resolve -- output was raw keep0. Fix: force
// need=1 on iteration 0 so every word is computed through f once; gating is exact
// thereafter (f pure in sources; unchanged sources => unchanged output => copy).
__device__ __forceinline__ u64 rl64(unsigned lo, unsigned hi, int l) {
  const unsigned a = (unsigned)__builtin_amdgcn_readlane((int)lo, l);
  const unsigned b = (unsigned)__builtin_amdgcn_readlane((int)hi, l);
  return ((u64)b << 32) | (u64)a;
}
__device__ __forceinline__ u64 rl64v(u64 v, int ln) {
  const unsigned a = (unsigned)__builtin_amdgcn_readlane((int)(unsigned)v, ln);
  const unsigned b = (unsigned)__builtin_amdgcn_readlane((int)(unsigned)(v >> 32), ln);
  return ((u64)b << 32) | (u64)a;
}
__device__ __forceinline__ u64 shflxor64(u64 v, int m) {
  const int lo = __shfl_xor((int)(unsigned)v, m);
  const int hi = __shfl_xor((int)(unsigned)(v >> 32), m);
  return ((u64)(unsigned)hi << 32) | (unsigned)lo;
}
__device__ __forceinline__ u64 build_alive(const float* sp) {
  u64 w = 0ull;
  const float4* p = (const float4*)sp;
  #pragma unroll
  for (int q = 0; q < 16; ++q) {
    const float4 s = p[q];
    if (s.x > POS_THRESH) w |= (1ull << (q * 4 + 0));
    if (s.y > POS_THRESH) w |= (1ull << (q * 4 + 1));
    if (s.z > POS_THRESH) w |= (1ull << (q * 4 + 2));
    if (s.w > POS_THRESH) w |= (1ull << (q * 4 + 3));
  }
  return w;
}

// v12 serial step; body guarded to t<256, barrier crossed by ALL waves.
#define NSTEPF(C_, MU, DU, MP, DP)                                              \
  do {                                                                          \
    if (t < 256) {                                                              \
      const int c_ = (C_);                                                      \
      const int e_ = extS[c_];                                                  \
      const u64 aw0v_ = alvS[c_];                                               \
      if (c_ + 1 < NWORDS) {                                                    \
        DP = maskT[(size_t)(c_ + 1) * NBOX + (size_t)(c_ + 1) * 64 + lane];     \
        const int en_ = extS[c_ + 1];                                           \
        const int t0n_ = c_ + 2 + wsub;                                         \
        if (t0n_ <= en_) {                                                      \
          const u64* cbp_ = maskT + (size_t)t0n_ * NBOX + (size_t)(c_ + 1) * 64 + sub * 8; \
          MP##0 = cbp_[0]; MP##1 = cbp_[1]; MP##2 = cbp_[2]; MP##3 = cbp_[3];   \
          MP##4 = cbp_[4]; MP##5 = cbp_[5]; MP##6 = cbp_[6]; MP##7 = cbp_[7];   \
        }                                                                       \
      }                                                                         \
      const unsigned awlo_ = (unsigned)__builtin_amdgcn_readfirstlane((int)(unsigned)(aw0v_ & 0xffffffffull)); \
      const unsigned awhi_ = (unsigned)__builtin_amdgcn_readfirstlane((int)(unsigned)(aw0v_ >> 32)); \
      const u64 aw0_ = ((u64)awhi_ << 32) | (u64)awlo_;                         \
      if (aw0_) {                                                               \
        const unsigned dlo_ = (unsigned)(DU & 0xffffffffull);                   \
        const unsigned dhi_ = (unsigned)(DU >> 32);                             \
        u64 aw_ = aw0_;                                                         \
        const bool sb_ = ((aw0_ >> lane) & 1ull) && ((DU & aw0_) != 0ull);      \
        u64 pending_ = __ballot(sb_ ? 1 : 0);                                   \
        while (pending_) {                                                      \
          const u64 p0_ = pending_;                                             \
          const u64 p1_ = p0_ & (p0_ - 1);                                      \
          const u64 p2_ = p1_ & (p1_ - 1);                                      \
          const u64 p3_ = p2_ & (p2_ - 1);                                      \
          const int b0_ = __builtin_ctzll(p0_);                                 \
          const int b1_ = p1_ ? __builtin_ctzll(p1_) : 64;                      \
          const int b2_ = p2_ ? __builtin_ctzll(p2_) : 64;                      \
          const int b3_ = p3_ ? __builtin_ctzll(p3_) : 64;                      \
          const u64 r0_ = rl64(dlo_, dhi_, b0_);                                \
          const u64 r1_ = rl64(dlo_, dhi_, b1_ & 63);                           \
          const u64 r2_ = rl64(dlo_, dhi_, b2_ & 63);                           \
          const u64 r3_ = rl64(dlo_, dhi_, b3_ & 63);                           \
          u64 supp_ = r0_;                                                      \
          u64 done_ = 1ull << b0_;                                              \
          const u64 k1_ = ((b1_ < 64) & !((supp_ >> (b1_ & 63)) & 1ull)) ? ~0ull : 0ull; \
          supp_ |= r1_ & k1_;  done_ |= (1ull << (b1_ & 63)) & k1_;             \
          const u64 k2_ = ((b2_ < 64) & !((supp_ >> (b2_ & 63)) & 1ull)) ? ~0ull : 0ull; \
          supp_ |= r2_ & k2_;  done_ |= (1ull << (b2_ & 63)) & k2_;             \
          const u64 k3_ = ((b3_ < 64) & !((supp_ >> (b3_ & 63)) & 1ull)) ? ~0ull : 0ull; \
          supp_ |= r3_ & k3_;  done_ |= (1ull << (b3_ & 63)) & k3_;             \
          aw_ &= ~supp_;                                                        \
          pending_ &= ~(supp_ | done_);                                         \
        }                                                                       \
        const int t0_ = c_ + 1 + wsub;                                          \
        if (t0_ <= e_) {                                                        \
          const unsigned oct_ = (unsigned)(aw_ >> (sub * 8)) & 0xffu;           \
          u64 sup_ = 0ull;                                                      \
          if (oct_ & 1u)   sup_ |= MU##0;                                       \
          if (oct_ & 2u)   sup_ |= MU##1;                                       \
          if (oct_ & 4u)   sup_ |= MU##2;                                       \
          if (oct_ & 8u)   sup_ |= MU##3;                                       \
          if (oct_ & 16u)  sup_ |= MU##4;                                       \
          if (oct_ & 32u)  sup_ |= MU##5;                                       \
          if (oct_ & 64u)  sup_ |= MU##6;                                       \
          if (oct_ & 128u) sup_ |= MU##7;                                       \
          if (sup_) atomicAnd((unsigned long long*)&alvS[t0_], ~sup_);          \
        }                                                                       \
        for (int base_ = c_ + 33; base_ <= e_; base_ += 32) {                   \
          const int tw_ = base_ + wsub;                                         \
          if (tw_ <= e_) {                                                      \
            const u64* cbp_ = maskT + (size_t)tw_ * NBOX + (size_t)c_ * 64 + sub * 8; \
            u64 m_[8];                                                          \
            _Pragma("unroll")                                                   \
            for (int j_ = 0; j_ < 8; ++j_) m_[j_] = cbp_[j_];                   \
            const unsigned oct_ = (unsigned)(aw_ >> (sub * 8)) & 0xffu;         \
            u64 sup_ = 0ull;                                                    \
            _Pragma("unroll")                                                   \
            for (int j_ = 0; j_ < 8; ++j_) if ((oct_ >> j_) & 1u) sup_ |= m_[j_]; \
            if (sup_) atomicAnd((unsigned long long*)&alvS[tw_], ~sup_);        \
          }                                                                     \
        }                                                                       \
        if (t == 0) alvS[c_] = aw_;                                             \
      }                                                                         \
    }                                                                           \
    asm volatile("s_waitcnt lgkmcnt(0)" ::: "memory");                          \
    __builtin_amdgcn_s_barrier();                                               \
    asm volatile("" ::: "memory");                                              \
  } while (0)

__global__ __launch_bounds__(1024) void nms_scan(
    const float* __restrict__ scores, const u64* __restrict__ maskT,
    const int* __restrict__ ext, u64* __restrict__ aliveOut)
{
  __shared__ u64 alvA[NWORDS], alvB[NWORDS], keep0S[NWORDS];
  __shared__ int extS[NWORDS], srcLoS[NWORDS];
  __shared__ int chgA[NWORDS], chgB[NWORDS];
  __shared__ int changedS;
  const int t = threadIdx.x;
  const int lane = t & 63;
  const int wv = t >> 6;          // 0..15
  const int g = lane >> 3;        // source-word group within window
  const int s = lane & 7;         // row octet
  const int wsub = t >> 3;        // fallback mapping (t<256)
  const int sub = t & 7;

  if (t < NWORDS) {
    const u64 wb = build_alive(scores + (size_t)t * 64);
    keep0S[t] = wb;
    alvA[t] = wb;
    extS[t] = ext[t];
    chgA[t] = 1;
  }
  if (t == 0) changedS = 0;
  __syncthreads();
  if (t < NWORDS) {
    int lo = t;
    for (int c = 0; c < t; ++c) if (extS[c] >= t) { lo = c; break; }
    srcLoS[t] = lo;
  }
  __syncthreads();

  // hoist the 12 per-wave diagonal rows (iteration-invariant) into registers
  u64 dgR[12];
  #pragma unroll
  for (int k = 0; k < 12; ++k) {
    const int w = wv + k * 16;
    dgR[k] = maskT[(size_t)w * NBOX + (size_t)w * 64 + lane];
  }

  // ---------------- change-gated parallel fixpoint phase ----------------
  int cur = 0, converged = 0;
  for (int it = 0; it < 64; ++it) {
    const u64* aOld = cur ? alvB : alvA;
    u64* aNew = cur ? alvA : alvB;
    const int* cOld = cur ? chgB : chgA;
    int* cNew = cur ? chgA : chgB;
    #pragma unroll
    for (int k = 0; k < 12; ++k) {
      const int w = wv + k * 16;
      const int lo = srcLoS[w];
      int need = (it == 0) ? 1 : 0;   // v18 FIX: every word computed through f once
      for (int c = lo; c < w; ++c) need |= cOld[c];
      if (!need) {
        if (lane == 0) { aNew[w] = aOld[w]; cNew[w] = 0; }
        continue;
      }
      const u64 dg = dgR[k];
      u64 supx = 0ull;
      for (int base = lo; base < w; base += 8) {
        const int c = base + g;
        u64 part = 0ull;
        if (c < w) {
          const u64 av = aOld[c];
          const unsigned oct = (unsigned)((av >> (s * 8)) & 0xffull);
          const u64* col = maskT + (size_t)w * NBOX + (size_t)c * 64 + s * 8;
          const u64 m0 = col[0], m1 = col[1], m2 = col[2], m3 = col[3];
          const u64 m4 = col[4], m5 = col[5], m6 = col[6], m7 = col[7];
          if (oct & 1u)   part |= m0;
          if (oct & 2u)   part |= m1;
          if (oct & 4u)   part |= m2;
          if (oct & 8u)   part |= m3;
          if (oct & 16u)  part |= m4;
          if (oct & 32u)  part |= m5;
          if (oct & 64u)  part |= m6;
          if (oct & 128u) part |= m7;
        }
        part |= shflxor64(part, 1);
        part |= shflxor64(part, 2);
        part |= shflxor64(part, 4);
        part |= shflxor64(part, 8);
        part |= shflxor64(part, 16);
        part |= shflxor64(part, 32);
        supx |= part;
      }
      // exact in-word greedy resolve on the externally-filtered base set
      const u64 b0v = keep0S[w] & ~supx;
      u64 aw = b0v;
      const bool sbv = ((b0v >> lane) & 1ull) && ((dg & b0v) != 0ull);
      u64 pending = __ballot(sbv ? 1 : 0);
      while (pending) {
        const u64 q0 = pending;
        const u64 q1 = q0 & (q0 - 1);
        const u64 q2 = q1 & (q1 - 1);
        const u64 q3 = q2 & (q2 - 1);
        const int c0 = __builtin_ctzll(q0);
        const int c1 = q1 ? __builtin_ctzll(q1) : 64;
        const int c2 = q2 ? __builtin_ctzll(q2) : 64;
        const int c3 = q3 ? __builtin_ctzll(q3) : 64;
        const u64 u0 = rl64v(dg, c0);
        const u64 u1 = rl64v(dg, c1 & 63);
        const u64 u2 = rl64v(dg, c2 & 63);
        const u64 u3 = rl64v(dg, c3 & 63);
        u64 sp = u0;
        u64 dn = 1ull << c0;
        const u64 g1 = ((c1 < 64) && !((sp >> (c1 & 63)) & 1ull)) ? ~0ull : 0ull;
        sp |= u1 & g1; dn |= (1ull << (c1 & 63)) & g1;
        const u64 g2 = ((c2 < 64) && !((sp >> (c2 & 63)) & 1ull)) ? ~0ull : 0ull;
        sp |= u2 & g2; dn |= (1ull << (c2 & 63)) & g2;
        const u64 g3 = ((c3 < 64) && !((sp >> (c3 & 63)) & 1ull)) ? ~0ull : 0ull;
        sp |= u3 & g3; dn |= (1ull << (c3 & 63)) & g3;
        aw &= ~sp;
        pending &= ~(sp | dn);
      }
      if (lane == 0) {
        aNew[w] = aw;
        const int ch = (aw != aOld[w]) ? 1 : 0;
        cNew[w] = ch;
        if (ch) changedS = 1;
      }
    }
    __syncthreads();                  // all writes done
    const int ch = changedS;          // everyone reads
    __syncthreads();                  // reads complete before reset
    cur ^= 1;                         // alv(cur) = newest
    if (!ch) { converged = 1; break; }
    if (t == 0) changedS = 0;
    __syncthreads();                  // reset visible before next writes
  }

  if (converged) {
    const u64* fin = cur ? alvB : alvA;
    if (t < NWORDS) aliveOut[t] = fin[t];
    return;
  }

  // ---------------- fallback: v12 serial scan (exact, all data intact) ----------------
  u64* alvS = alvA;
  if (t < NWORDS) alvS[t] = keep0S[t];
  __syncthreads();

  u64 mA0 = 0, mA1 = 0, mA2 = 0, mA3 = 0, mA4 = 0, mA5 = 0, mA6 = 0, mA7 = 0;
  u64 mB0 = 0, mB1 = 0, mB2 = 0, mB3 = 0, mB4 = 0, mB5 = 0, mB6 = 0, mB7 = 0;
  u64 dgA = 0, dgB = 0;
  if (t < 256) {
    const int e0f = extS[0];
    if (1 + wsub <= e0f) {
      const u64* cbp = maskT + (size_t)(1 + wsub) * NBOX + sub * 8;
      mA0 = cbp[0]; mA1 = cbp[1]; mA2 = cbp[2]; mA3 = cbp[3];
      mA4 = cbp[4]; mA5 = cbp[5]; mA6 = cbp[6]; mA7 = cbp[7];
    }
    dgA = maskT[lane];
  }
  asm volatile("s_waitcnt lgkmcnt(0)" ::: "memory");
  __builtin_amdgcn_s_barrier();
  asm volatile("" ::: "memory");

  for (int c = 0; c < NWORDS; c += 2) {
    NSTEPF(c,     mA, dgA, mB, dgB);
    NSTEPF(c + 1, mB, dgB, mA, dgA);
  }
  if (t < NWORDS) aliveOut[t] = alvS[t];
}

// ---------------- Kernel 5: masked output ----------------
__global__ __launch_bounds__(256) void write_output(
    const float* __restrict__ boxes, const u64* __restrict__ alive,
    float* __restrict__ out)
{
  const int i = blockIdx.x * 256 + threadIdx.x;
  if (i < NBOX) {
    const bool k = (alive[i >> 6] >> (i & 63)) & 1ull;
    const float4 b = *(const float4*)&boxes[i * 4];
    const float4 z = {0.f, 0.f, 0.f, 0.f};
    *(float4*)&out[i * 4] = k ? b : z;
  }
}

extern "C" void kernel_launch(void* const* d_in, const int* in_sizes, int n_in,
                              void* d_out, int out_size, void* d_ws, size_t ws_size,
                              hipStream_t stream) {
  const float* X    = (const float*)d_in[0];  // (1,64,64,1024)
  const float* Wc   = (const float*)d_in[1];  // (3,3,1024,512)
  const float* Bc   = (const float*)d_in[2];  // (512,)
  const float* Wcls = (const float*)d_in[3];  // (1,1,512,6)
  const float* bcls = (const float*)d_in[4];  // (6,)
  const float* Wreg = (const float*)d_in[5];  // (1,1,512,12)
  const float* breg = (const float*)d_in[6];  // (12,)

  char* ws = (char*)d_ws;
  const size_t NEED_BIG = 52676864ull;   // Y4(33.55M)+misc+WT/maskT(18.87M)

  if (ws_size >= NEED_BIG) {
    // ---- partial-plane layout: no atomics, no zero_y ----
    float*     Y4     = (float*)    (ws);                  // 33,554,432 B (4 planes)
    float*     boxes  = (float*)    (ws + 33554432);       //    196,608 B
    float*     scores = (float*)    (ws + 33751040);       //     49,152 B
    u64*       aliveG = (u64*)      (ws + 33800192);       //      1,536 B
    int*       extG   = (int*)      (ws + 33801728);       //        768 B
    _Float16*  WTh    = (_Float16*) (ws + 33802496);       //  9,437,184 B
    _Float16*  WTl    = (_Float16*) (ws + 43239680);       //  9,437,184 B
    u64*       maskT  = (u64*)      (ws + 33802496);       // 18,874,368 B (post-conv reuse)

    prep_wt     <<<1152, 256, 0, stream>>>(Wc, WTh, WTl);
    conv_mfma   <<<512, 256, 0, stream>>>(X, WTh, WTl, Y4, 1);
    heads_decode<<<4096, 64, 0, stream>>>(Y4, 4, Bc, Wcls, bcls, Wreg, breg, boxes, scores, extG);
    build_mask  <<<dim3(192, 192), 256, 0, stream>>>(boxes, maskT, extG);
    nms_scan    <<<1, 1024, 0, stream>>>(scores, maskT, extG, aliveG);
    write_output<<<48, 256, 0, stream>>>(boxes, aliveG, (float*)d_out);
  } else {
    // ---- legacy layout: single Y, zero_y + atomicAdd ----
    float*     Y      = (float*)    (ws);                 // 8,388,608 B
    float*     boxes  = (float*)    (ws + 8388608);       //   196,608 B
    float*     scores = (float*)    (ws + 8585216);       //    49,152 B
    u64*       aliveG = (u64*)      (ws + 8634368);       //     1,536 B
    int*       extG   = (int*)      (ws + 8635904);       //       768 B
    _Float16*  WTh    = (_Float16*) (ws + 8636672);       // 9,437,184 B
    _Float16*  WTl    = (_Float16*) (ws + 18073856);      // 9,437,184 B
    u64*       maskT  = (u64*)      (ws + 8636672);       // 18,874,368 B (post-conv)

    zero_y      <<<2048, 256, 0, stream>>>((float4*)Y);
    prep_wt     <<<1152, 256, 0, stream>>>(Wc, WTh, WTl);
    conv_mfma   <<<512, 256, 0, stream>>>(X, WTh, WTl, Y, 0);
    heads_decode<<<4096, 64, 0, stream>>>(Y, 1, Bc, Wcls, bcls, Wreg, breg, boxes, scores, extG);
    build_mask  <<<dim3(192, 192), 256, 0, stream>>>(boxes, maskT, extG);
    nms_scan    <<<1, 1024, 0, stream>>>(scores, maskT, extG, aliveG);
    write_output<<<48, 256, 0, stream>>>(boxes, aliveG, (float*)d_out);
  }
}

// Round 19
// 436.005 us; speedup vs baseline: 1.1347x; 1.1347x over previous
//
#include <hip/hip_runtime.h>
#include <cstdint>

#define NBOX 12288
#define NWORDS 192
#define POS_THRESH 0.15f
#define NMS_THRESH 0.7f

typedef unsigned long long u64;
typedef _Float16 half8 __attribute__((ext_vector_type(8)));
typedef float floatx4 __attribute__((ext_vector_type(4)));

// ---------------- Kernel 0a: zero the conv accumulator (fallback path only) ----------------
__global__ __launch_bounds__(256) void zero_y(float4* __restrict__ Y) {
  Y[blockIdx.x * 256 + threadIdx.x] = float4{0.f, 0.f, 0.f, 0.f};
}

// ---------------- Kernel 0b: W (3,3,1024,512) -> WT[tap][n][c] fp16 h/l split ----------------
// l pre-scaled by 4096 so it stays in fp16 normal range.
__global__ __launch_bounds__(256) void prep_wt(
    const float* __restrict__ Wc, _Float16* __restrict__ WTh, _Float16* __restrict__ WTl)
{
  __shared__ float tile[64][65];
  const int b = blockIdx.x;           // 9 taps * 16 c-tiles * 8 n-tiles = 1152
  const int tap = b >> 7;
  const int rem = b & 127;
  const int c0 = (rem >> 3) * 64, n0 = (rem & 7) * 64;
  const int t = threadIdx.x;
  #pragma unroll
  for (int i = 0; i < 16; ++i) {
    const int idx = i * 256 + t;
    const int c = idx >> 6, n = idx & 63;
    tile[n][c] = Wc[((size_t)(tap * 1024 + c0 + c)) * 512 + n0 + n];
  }
  __syncthreads();
  #pragma unroll
  for (int i = 0; i < 16; ++i) {
    const int idx = i * 256 + t;
    const int n = idx >> 6, c = idx & 63;
    const float v = tile[n][c];
    const _Float16 h = (_Float16)v;
    const _Float16 l = (_Float16)((v - (float)h) * 4096.0f);
    const size_t o = ((size_t)(tap * 512 + n0 + n)) * 1024 + c0 + c;
    WTh[o] = h;
    WTl[o] = l;
  }
}

// ---------------- Kernel 1: 3x3 conv via split-fp16 MFMA (v14 = best measured) ----------------
#define AROW 40                 // 32 k-halves padded to 40
#define AS_PLANE (4 * 66 * AROW)
#define BS_PLANE (128 * AROW)
#define YPLANE 2097152          // 4096*512 floats
__global__ __launch_bounds__(256, 2) void conv_mfma(
    const float* __restrict__ X, const _Float16* __restrict__ WTh,
    const _Float16* __restrict__ WTl, float* __restrict__ Y, int partial)
{
  __shared__ _Float16 As[2 * AS_PLANE];   // 42,240 B
  __shared__ _Float16 Bs[2 * BS_PLANE];   // 20,480 B
  const int bid = blockIdx.x;
  const int ks = bid & 3;                 // 4 K-slices of 256 ch
  const int nt = (bid >> 2) & 3;
  const int mt = bid >> 4;
  const int t = threadIdx.x;
  const int lane = t & 63, wid = t >> 6;
  const int wm = wid >> 1, wn = wid & 1;
  const int lrow = lane & 15, quad = lane >> 4;

  floatx4 accH[4][4], accL[4][4];
  #pragma unroll
  for (int i = 0; i < 4; ++i)
    #pragma unroll
    for (int j = 0; j < 4; ++j) { accH[i][j] = (floatx4)0.f; accL[i][j] = (floatx4)0.f; }

  for (int kc = 0; kc < 8; ++kc) {
    const int c0 = ks * 256 + kc * 32;
    __syncthreads();   // prior chunk readers done
    for (int r = t; r < 264; r += 256) {
      const int yy = r / 66;
      const int xx = r - yy * 66;
      const int yi = mt * 2 + yy - 1;
      const int xi = xx - 1;
      const int akey = (r >> 3) & 3;
      _Float16* dsth = &As[r * AROW];
      _Float16* dstl = dsth + AS_PLANE;
      if (yi >= 0 && yi < 64 && xi >= 0 && xi < 64) {
        const float4* src = (const float4*)(X + ((size_t)(yi * 64 + xi)) * 1024 + c0);
        #pragma unroll
        for (int j = 0; j < 4; ++j) {
          const float4 va = src[2 * j], vb = src[2 * j + 1];
          const float f[8] = {va.x, va.y, va.z, va.w, vb.x, vb.y, vb.z, vb.w};
          half8 hh, hl;
          #pragma unroll
          for (int e = 0; e < 8; ++e) {
            const _Float16 h = (_Float16)f[e];
            hh[e] = h;
            hl[e] = (_Float16)((f[e] - (float)h) * 4096.0f);
          }
          const int sl = (j ^ akey) * 8;
          *(half8*)&dsth[sl] = hh;
          *(half8*)&dstl[sl] = hl;
        }
      } else {
        const half8 z = (half8)(_Float16)0.f;
        #pragma unroll
        for (int j = 0; j < 4; ++j) { *(half8*)&dsth[j * 8] = z; *(half8*)&dstl[j * 8] = z; }
      }
    }
    for (int tap = 0; tap < 9; ++tap) {
      if (tap > 0) __syncthreads();   // prior tap's B readers done
      {   // ---- stage B: 256 rows (hl,n) x 32 halves, slot-swizzled ----
        const int hl = t >> 7, n = t & 127;
        const int bkey = (n >> 3) & 3;
        const _Float16* src = (hl ? WTl : WTh) +
            ((size_t)(tap * 512 + nt * 128 + n)) * 1024 + c0;
        _Float16* dst = &Bs[hl * BS_PLANE + n * AROW];
        #pragma unroll
        for (int j = 0; j < 4; ++j)
          *(half8*)&dst[(j ^ bkey) * 8] = *(const half8*)&src[j * 8];
      }
      __syncthreads();   // A (first tap) + B visible
      const int dy = tap / 3 - 1, dx = tap - (tap / 3) * 3 - 1;
      const int yy = wm + dy + 1;
      const int xxb = dx + 1;
      half8 Ah[4], Al[4], Bh[4], Bl[4];
      #pragma unroll
      for (int fm = 0; fm < 4; ++fm) {
        const int row = yy * 66 + xxb + fm * 16 + lrow;
        const int idx = row * AROW + ((quad ^ ((row >> 3) & 3)) * 8);
        Ah[fm] = *(const half8*)&As[idx];
        Al[fm] = *(const half8*)&As[idx + AS_PLANE];
      }
      #pragma unroll
      for (int fn = 0; fn < 4; ++fn) {
        const int row = wn * 64 + fn * 16 + lrow;
        const int idx = row * AROW + ((quad ^ ((row >> 3) & 3)) * 8);
        Bh[fn] = *(const half8*)&Bs[idx];
        Bl[fn] = *(const half8*)&Bs[idx + BS_PLANE];
      }
      #pragma unroll
      for (int fm = 0; fm < 4; ++fm)
        #pragma unroll
        for (int fn = 0; fn < 4; ++fn) {
          accH[fm][fn] = __builtin_amdgcn_mfma_f32_16x16x32_f16(Ah[fm], Bh[fn], accH[fm][fn], 0, 0, 0);
          accL[fm][fn] = __builtin_amdgcn_mfma_f32_16x16x32_f16(Al[fm], Bh[fn], accL[fm][fn], 0, 0, 0);
          accL[fm][fn] = __builtin_amdgcn_mfma_f32_16x16x32_f16(Ah[fm], Bl[fn], accL[fm][fn], 0, 0, 0);
        }
    }
  }
  // ---- epilogue ----
  const int m0 = mt * 128 + wm * 64;
  const int n0 = nt * 128 + wn * 64;
  if (partial) {
    float* Yp = Y + (size_t)ks * YPLANE;
    #pragma unroll
    for (int fm = 0; fm < 4; ++fm)
      #pragma unroll
      for (int fn = 0; fn < 4; ++fn) {
        const int n = n0 + fn * 16 + lrow;
        #pragma unroll
        for (int r = 0; r < 4; ++r) {
          const int m = m0 + fm * 16 + quad * 4 + r;
          Yp[(size_t)m * 512 + n] = accH[fm][fn][r] + accL[fm][fn][r] * (1.0f / 4096.0f);
        }
      }
  } else {
    #pragma unroll
    for (int fm = 0; fm < 4; ++fm)
      #pragma unroll
      for (int fn = 0; fn < 4; ++fn) {
        const int n = n0 + fn * 16 + lrow;
        #pragma unroll
        for (int r = 0; r < 4; ++r) {
          const int m = m0 + fm * 16 + quad * 4 + r;
          atomicAdd(&Y[(size_t)m * 512 + n],
                    accH[fm][fn][r] + accL[fm][fn][r] * (1.0f / 4096.0f));
        }
      }
  }
}

// ---------------- Kernel 2: bias+ReLU + 1x1 heads + softmax(6) + decode + ext init ----------------
__global__ __launch_bounds__(64) void heads_decode(
    const float* __restrict__ Yx, int nparts, const float* __restrict__ Bc,
    const float* __restrict__ Wcls, const float* __restrict__ bcls,
    const float* __restrict__ Wreg, const float* __restrict__ breg,
    float* __restrict__ boxes, float* __restrict__ scores, int* __restrict__ ext)
{
  __shared__ float xs[512];
  const int pos = blockIdx.x;
  const int l = threadIdx.x;
  if (l == 0 && pos < NWORDS) ext[pos] = pos;
  float4 v0 = {0.f, 0.f, 0.f, 0.f};
  float4 v1 = {0.f, 0.f, 0.f, 0.f};
  for (int p = 0; p < nparts; ++p) {
    const float* xrow = Yx + (size_t)p * YPLANE + (size_t)pos * 512;
    const float4 a = *(const float4*)&xrow[l * 8];
    const float4 b = *(const float4*)&xrow[l * 8 + 4];
    v0.x += a.x; v0.y += a.y; v0.z += a.z; v0.w += a.w;
    v1.x += b.x; v1.y += b.y; v1.z += b.z; v1.w += b.w;
  }
  const float4 b0 = *(const float4*)&Bc[l * 8];
  const float4 b1 = *(const float4*)&Bc[l * 8 + 4];
  xs[l * 8 + 0] = fmaxf(v0.x + b0.x, 0.f);
  xs[l * 8 + 1] = fmaxf(v0.y + b0.y, 0.f);
  xs[l * 8 + 2] = fmaxf(v0.z + b0.z, 0.f);
  xs[l * 8 + 3] = fmaxf(v0.w + b0.w, 0.f);
  xs[l * 8 + 4] = fmaxf(v1.x + b1.x, 0.f);
  xs[l * 8 + 5] = fmaxf(v1.y + b1.y, 0.f);
  xs[l * 8 + 6] = fmaxf(v1.z + b1.z, 0.f);
  xs[l * 8 + 7] = fmaxf(v1.w + b1.w, 0.f);
  __syncthreads();

  const float* wp;
  int oc;
  float bini;
  if (l < 6)       { wp = Wcls + l;       oc = 6;  bini = bcls[l]; }
  else if (l < 18) { wp = Wreg + (l - 6); oc = 12; bini = breg[l - 6]; }
  else             { wp = Wcls;           oc = 0;  bini = 0.f; }
  float acc = bini;
  const float* p = wp;
  #pragma unroll 4
  for (int c = 0; c < 512; ++c) { acc = fmaf(xs[c], *p, acc); p += oc; }

  const float l0 = __shfl(acc, 0), l1 = __shfl(acc, 1), l2 = __shfl(acc, 2);
  const float l3 = __shfl(acc, 3), l4 = __shfl(acc, 4), l5 = __shfl(acc, 5);
  const int a = (l < 3) ? l : 0;
  const float d0 = __shfl(acc, 6 + a * 4 + 0);
  const float d1 = __shfl(acc, 6 + a * 4 + 1);
  const float d2 = __shfl(acc, 6 + a * 4 + 2);
  const float d3 = __shfl(acc, 6 + a * 4 + 3);

  const float mx = fmaxf(fmaxf(fmaxf(l0, l1), fmaxf(l2, l3)), fmaxf(l4, l5));
  const float e0 = expf(l0 - mx), e1 = expf(l1 - mx), e2 = expf(l2 - mx);
  const float e3 = expf(l3 - mx), e4 = expf(l4 - mx), e5 = expf(l5 - mx);
  const float den = ((((e0 + e1) + e2) + e3) + e4) + e5;
  const float esel = (a == 0) ? e1 : ((a == 1) ? e3 : e5);
  const float sc = esel / den;

  const int px = pos & 63, py = pos >> 6;
  const float cx = (px + 0.5f) * 16.0f;
  const float cy = (py + 0.5f) * 16.0f;
  const float ratio = (a == 0) ? 0.5f : ((a == 1) ? 1.0f : 2.0f);
  const float sq = sqrtf(ratio);
  const float wsz = 128.0f * sq;
  const float hsz = 128.0f / sq;
  const float a0 = cx - wsz * 0.5f;
  const float a1 = cy - hsz * 0.5f;
  const float a2 = cx + wsz * 0.5f;
  const float a3 = cy + hsz * 0.5f;
  const float w = a2 - a0, h = a3 - a1;
  const float xc = __fadd_rn(__fmul_rn(__fadd_rn(a0, a2), 0.5f), __fmul_rn(d0, w));
  const float yc = __fadd_rn(__fmul_rn(__fadd_rn(a1, a3), 0.5f), __fmul_rn(d1, h));
  const float nw = __fmul_rn(w, expf(d2));
  const float nh = __fmul_rn(h, expf(d3));
  float4 box;
  box.x = __fsub_rn(xc, __fmul_rn(nw, 0.5f));
  box.y = __fsub_rn(yc, __fmul_rn(nh, 0.5f));
  box.z = __fadd_rn(xc, __fmul_rn(nw, 0.5f));
  box.w = __fadd_rn(yc, __fmul_rn(nh, 0.5f));

  if (l < 3) {
    const int idx = pos * 3 + a;
    *(float4*)&boxes[idx * 4] = box;
    scores[idx] = sc;
  }
}

// ---------------- Kernel 3: suppression bit-matrix (column-major) + extent ----------------
__global__ __launch_bounds__(256) void build_mask(
    const float* __restrict__ boxes, u64* __restrict__ maskT,
    int* __restrict__ ext)
{
  const int w  = blockIdx.x;
  const int ci = blockIdx.y;
  if (w < ci) return;
  __shared__ float4 rb[64];
  __shared__ int anyf;
  const int t = threadIdx.x;
  const int lane = t & 63, wid = t >> 6;
  if (t == 0) anyf = 0;
  if (t < 64) rb[t] = *(const float4*)&boxes[(ci * 64 + t) * 4];
  const float4 cb = *(const float4*)&boxes[(w * 64 + lane) * 4];
  const float careaa = __fmul_rn(cb.z - cb.x, cb.w - cb.y);
  const int jglob = w * 64 + lane;
  __syncthreads();
  bool any = false;
  for (int rr = 0; rr < 16; ++rr) {
    const int r = wid * 16 + rr;
    const int row = ci * 64 + r;
    const float4 rx = rb[r];
    const float ra = __fmul_rn(rx.z - rx.x, rx.w - rx.y);
    const float xx1 = fmaxf(rx.x, cb.x);
    const float yy1 = fmaxf(rx.y, cb.y);
    const float xx2 = fminf(rx.z, cb.z);
    const float yy2 = fminf(rx.w, cb.w);
    const float iw = fmaxf(__fsub_rn(xx2, xx1), 0.f);
    const float ih = fmaxf(__fsub_rn(yy2, yy1), 0.f);
    const float inter = __fmul_rn(iw, ih);
    const float den = __fadd_rn(__fsub_rn(__fadd_rn(ra, careaa), inter), 1e-9f);
    const float iou = __fdiv_rn(inter, den);
    const bool bit = (iou > NMS_THRESH) && (jglob > row);
    any |= bit;
    const u64 word = __ballot(bit ? 1 : 0);
    if (lane == 0) maskT[(size_t)w * NBOX + row] = word;
  }
  if (any) anyf = 1;
  __syncthreads();
  if (t == 0 && anyf && w > ci) atomicMax(&ext[ci], w);
}

// ---------------- Kernel 4: NMS, v19: in-place Gauss-Seidel sweeps + serial fallback ----
// v16/v18 Jacobi needed ~50 iterations (one dependency level each); cost = iters x
// barrier overhead. v19: wave wv sweeps its CONTIGUOUS stripe [12wv,12wv+12) in
// ascending order IN PLACE -- intra-stripe chains collapse in one sweep; cross-stripe
// propagation <= 1 sweep/boundary. Exact: a zero-change sweep means every word was
// verified as f(values unchanged throughout the sweep) => alvS = f(alvS) => fixpoint
// => unique greedy solution. Racy cross-stripe reads only delay convergence (u64 LDS
// ops don't tear). v12 serial fallback if >64 sweeps (adversarial only).
__device__ __forceinline__ u64 rl64(unsigned lo, unsigned hi, int l) {
  const unsigned a = (unsigned)__builtin_amdgcn_readlane((int)lo, l);
  const unsigned b = (unsigned)__builtin_amdgcn_readlane((int)hi, l);
  return ((u64)b << 32) | (u64)a;
}
__device__ __forceinline__ u64 rl64v(u64 v, int ln) {
  const unsigned a = (unsigned)__builtin_amdgcn_readlane((int)(unsigned)v, ln);
  const unsigned b = (unsigned)__builtin_amdgcn_readlane((int)(unsigned)(v >> 32), ln);
  return ((u64)b << 32) | (u64)a;
}
__device__ __forceinline__ u64 shflxor64(u64 v, int m) {
  const int lo = __shfl_xor((int)(unsigned)v, m);
  const int hi = __shfl_xor((int)(unsigned)(v >> 32), m);
  return ((u64)(unsigned)hi << 32) | (unsigned)lo;
}
__device__ __forceinline__ u64 build_alive(const float* sp) {
  u64 w = 0ull;
  const float4* p = (const float4*)sp;
  #pragma unroll
  for (int q = 0; q < 16; ++q) {
    const float4 s = p[q];
    if (s.x > POS_THRESH) w |= (1ull << (q * 4 + 0));
    if (s.y > POS_THRESH) w |= (1ull << (q * 4 + 1));
    if (s.z > POS_THRESH) w |= (1ull << (q * 4 + 2));
    if (s.w > POS_THRESH) w |= (1ull << (q * 4 + 3));
  }
  return w;
}

// v12 serial step; body guarded to t<256, barrier crossed by ALL waves.
#define NSTEPF(C_, MU, DU, MP, DP)                                              \
  do {                                                                          \
    if (t < 256) {                                                              \
      const int c_ = (C_);                                                      \
      const int e_ = extS[c_];                                                  \
      const u64 aw0v_ = alvS[c_];                                               \
      if (c_ + 1 < NWORDS) {                                                    \
        DP = maskT[(size_t)(c_ + 1) * NBOX + (size_t)(c_ + 1) * 64 + lane];     \
        const int en_ = extS[c_ + 1];                                           \
        const int t0n_ = c_ + 2 + wsub;                                         \
        if (t0n_ <= en_) {                                                      \
          const u64* cbp_ = maskT + (size_t)t0n_ * NBOX + (size_t)(c_ + 1) * 64 + sub * 8; \
          MP##0 = cbp_[0]; MP##1 = cbp_[1]; MP##2 = cbp_[2]; MP##3 = cbp_[3];   \
          MP##4 = cbp_[4]; MP##5 = cbp_[5]; MP##6 = cbp_[6]; MP##7 = cbp_[7];   \
        }                                                                       \
      }                                                                         \
      const unsigned awlo_ = (unsigned)__builtin_amdgcn_readfirstlane((int)(unsigned)(aw0v_ & 0xffffffffull)); \
      const unsigned awhi_ = (unsigned)__builtin_amdgcn_readfirstlane((int)(unsigned)(aw0v_ >> 32)); \
      const u64 aw0_ = ((u64)awhi_ << 32) | (u64)awlo_;                         \
      if (aw0_) {                                                               \
        const unsigned dlo_ = (unsigned)(DU & 0xffffffffull);                   \
        const unsigned dhi_ = (unsigned)(DU >> 32);                             \
        u64 aw_ = aw0_;                                                         \
        const bool sb_ = ((aw0_ >> lane) & 1ull) && ((DU & aw0_) != 0ull);      \
        u64 pending_ = __ballot(sb_ ? 1 : 0);                                   \
        while (pending_) {                                                      \
          const u64 p0_ = pending_;                                             \
          const u64 p1_ = p0_ & (p0_ - 1);                                      \
          const u64 p2_ = p1_ & (p1_ - 1);                                      \
          const u64 p3_ = p2_ & (p2_ - 1);                                      \
          const int b0_ = __builtin_ctzll(p0_);                                 \
          const int b1_ = p1_ ? __builtin_ctzll(p1_) : 64;                      \
          const int b2_ = p2_ ? __builtin_ctzll(p2_) : 64;                      \
          const int b3_ = p3_ ? __builtin_ctzll(p3_) : 64;                      \
          const u64 r0_ = rl64(dlo_, dhi_, b0_);                                \
          const u64 r1_ = rl64(dlo_, dhi_, b1_ & 63);                           \
          const u64 r2_ = rl64(dlo_, dhi_, b2_ & 63);                           \
          const u64 r3_ = rl64(dlo_, dhi_, b3_ & 63);                           \
          u64 supp_ = r0_;                                                      \
          u64 done_ = 1ull << b0_;                                              \
          const u64 k1_ = ((b1_ < 64) & !((supp_ >> (b1_ & 63)) & 1ull)) ? ~0ull : 0ull; \
          supp_ |= r1_ & k1_;  done_ |= (1ull << (b1_ & 63)) & k1_;             \
          const u64 k2_ = ((b2_ < 64) & !((supp_ >> (b2_ & 63)) & 1ull)) ? ~0ull : 0ull; \
          supp_ |= r2_ & k2_;  done_ |= (1ull << (b2_ & 63)) & k2_;             \
          const u64 k3_ = ((b3_ < 64) & !((supp_ >> (b3_ & 63)) & 1ull)) ? ~0ull : 0ull; \
          supp_ |= r3_ & k3_;  done_ |= (1ull << (b3_ & 63)) & k3_;             \
          aw_ &= ~supp_;                                                        \
          pending_ &= ~(supp_ | done_);                                         \
        }                                                                       \
        const int t0_ = c_ + 1 + wsub;                                          \
        if (t0_ <= e_) {                                                        \
          const unsigned oct_ = (unsigned)(aw_ >> (sub * 8)) & 0xffu;           \
          u64 sup_ = 0ull;                                                      \
          if (oct_ & 1u)   sup_ |= MU##0;                                       \
          if (oct_ & 2u)   sup_ |= MU##1;                                       \
          if (oct_ & 4u)   sup_ |= MU##2;                                       \
          if (oct_ & 8u)   sup_ |= MU##3;                                       \
          if (oct_ & 16u)  sup_ |= MU##4;                                       \
          if (oct_ & 32u)  sup_ |= MU##5;                                       \
          if (oct_ & 64u)  sup_ |= MU##6;                                       \
          if (oct_ & 128u) sup_ |= MU##7;                                       \
          if (sup_) atomicAnd((unsigned long long*)&alvS[t0_], ~sup_);          \
        }                                                                       \
        for (int base_ = c_ + 33; base_ <= e_; base_ += 32) {                   \
          const int tw_ = base_ + wsub;                                         \
          if (tw_ <= e_) {                                                      \
            const u64* cbp_ = maskT + (size_t)tw_ * NBOX + (size_t)c_ * 64 + sub * 8; \
            u64 m_[8];                                                          \
            _Pragma("unroll")                                                   \
            for (int j_ = 0; j_ < 8; ++j_) m_[j_] = cbp_[j_];                   \
            const unsigned oct_ = (unsigned)(aw_ >> (sub * 8)) & 0xffu;         \
            u64 sup_ = 0ull;                                                    \
            _Pragma("unroll")                                                   \
            for (int j_ = 0; j_ < 8; ++j_) if ((oct_ >> j_) & 1u) sup_ |= m_[j_]; \
            if (sup_) atomicAnd((unsigned long long*)&alvS[tw_], ~sup_);        \
          }                                                                     \
        }                                                                       \
        if (t == 0) alvS[c_] = aw_;                                             \
      }                                                                         \
    }                                                                           \
    asm volatile("s_waitcnt lgkmcnt(0)" ::: "memory");                          \
    __builtin_amdgcn_s_barrier();                                               \
    asm volatile("" ::: "memory");                                              \
  } while (0)

__global__ __launch_bounds__(1024) void nms_scan(
    const float* __restrict__ scores, const u64* __restrict__ maskT,
    const int* __restrict__ ext, u64* __restrict__ aliveOut)
{
  __shared__ u64 alvS[NWORDS], keep0S[NWORDS];
  __shared__ int extS[NWORDS], srcLoS[NWORDS];
  __shared__ int changedS;
  const int t = threadIdx.x;
  const int lane = t & 63;
  const int wv = t >> 6;          // 0..15: stripe index (12 contiguous words)
  const int g = lane >> 3;        // source-word group within window
  const int s = lane & 7;         // row octet
  const int wsub = t >> 3;        // fallback mapping (t<256)
  const int sub = t & 7;

  if (t < NWORDS) {
    const u64 wb = build_alive(scores + (size_t)t * 64);
    keep0S[t] = wb;
    alvS[t] = wb;
    extS[t] = ext[t];
  }
  if (t == 0) changedS = 0;
  __syncthreads();
  if (t < NWORDS) {
    int lo = t;
    for (int c = 0; c < t; ++c) if (extS[c] >= t) { lo = c; break; }
    srcLoS[t] = lo;
  }
  __syncthreads();

  // hoist the stripe's 12 diagonal rows (iteration-invariant) into registers
  u64 dgR[12];
  #pragma unroll
  for (int k = 0; k < 12; ++k) {
    const int w = wv * 12 + k;
    dgR[k] = maskT[(size_t)w * NBOX + (size_t)w * 64 + lane];
  }

  // ---------------- in-place Gauss-Seidel sweeps ----------------
  int converged = 0;
  for (int it = 0; it < 64; ++it) {
    #pragma unroll
    for (int k = 0; k < 12; ++k) {
      const int w = wv * 12 + k;
      const int lo = srcLoS[w];
      const u64 dg = dgR[k];
      u64 supx = 0ull;
      for (int base = lo; base < w; base += 8) {
        const int c = base + g;
        u64 part = 0ull;
        if (c < w) {
          const u64 av = alvS[c];           // in-place read (GS)
          const unsigned oct = (unsigned)((av >> (s * 8)) & 0xffull);
          const u64* col = maskT + (size_t)w * NBOX + (size_t)c * 64 + s * 8;
          const u64 m0 = col[0], m1 = col[1], m2 = col[2], m3 = col[3];
          const u64 m4 = col[4], m5 = col[5], m6 = col[6], m7 = col[7];
          if (oct & 1u)   part |= m0;
          if (oct & 2u)   part |= m1;
          if (oct & 4u)   part |= m2;
          if (oct & 8u)   part |= m3;
          if (oct & 16u)  part |= m4;
          if (oct & 32u)  part |= m5;
          if (oct & 64u)  part |= m6;
          if (oct & 128u) part |= m7;
        }
        part |= shflxor64(part, 1);
        part |= shflxor64(part, 2);
        part |= shflxor64(part, 4);
        part |= shflxor64(part, 8);
        part |= shflxor64(part, 16);
        part |= shflxor64(part, 32);
        supx |= part;
      }
      // exact in-word greedy resolve on the externally-filtered base set
      const u64 b0v = keep0S[w] & ~supx;
      u64 aw = b0v;
      const bool sbv = ((b0v >> lane) & 1ull) && ((dg & b0v) != 0ull);
      u64 pending = __ballot(sbv ? 1 : 0);
      while (pending) {
        const u64 q0 = pending;
        const u64 q1 = q0 & (q0 - 1);
        const u64 q2 = q1 & (q1 - 1);
        const u64 q3 = q2 & (q2 - 1);
        const int c0 = __builtin_ctzll(q0);
        const int c1 = q1 ? __builtin_ctzll(q1) : 64;
        const int c2 = q2 ? __builtin_ctzll(q2) : 64;
        const int c3 = q3 ? __builtin_ctzll(q3) : 64;
        const u64 u0 = rl64v(dg, c0);
        const u64 u1 = rl64v(dg, c1 & 63);
        const u64 u2 = rl64v(dg, c2 & 63);
        const u64 u3 = rl64v(dg, c3 & 63);
        u64 sp = u0;
        u64 dn = 1ull << c0;
        const u64 g1 = ((c1 < 64) && !((sp >> (c1 & 63)) & 1ull)) ? ~0ull : 0ull;
        sp |= u1 & g1; dn |= (1ull << (c1 & 63)) & g1;
        const u64 g2 = ((c2 < 64) && !((sp >> (c2 & 63)) & 1ull)) ? ~0ull : 0ull;
        sp |= u2 & g2; dn |= (1ull << (c2 & 63)) & g2;
        const u64 g3 = ((c3 < 64) && !((sp >> (c3 & 63)) & 1ull)) ? ~0ull : 0ull;
        sp |= u3 & g3; dn |= (1ull << (c3 & 63)) & g3;
        aw &= ~sp;
        pending &= ~(sp | dn);
      }
      if (lane == 0) {
        if (aw != alvS[w]) { alvS[w] = aw; changedS = 1; }
      }
      asm volatile("s_waitcnt lgkmcnt(0)" ::: "memory");  // stripe write visible to next k
    }
    __syncthreads();                  // sweep complete
    const int ch = changedS;          // everyone reads
    __syncthreads();                  // reads complete before reset
    if (!ch) { converged = 1; break; }
    if (t == 0) changedS = 0;
    __syncthreads();                  // reset visible before next sweep
  }

  if (converged) {
    if (t < NWORDS) aliveOut[t] = alvS[t];
    return;
  }

  // ---------------- fallback: v12 serial scan (exact, all data intact) ----------------
  if (t < NWORDS) alvS[t] = keep0S[t];
  __syncthreads();

  u64 mA0 = 0, mA1 = 0, mA2 = 0, mA3 = 0, mA4 = 0, mA5 = 0, mA6 = 0, mA7 = 0;
  u64 mB0 = 0, mB1 = 0, mB2 = 0, mB3 = 0, mB4 = 0, mB5 = 0, mB6 = 0, mB7 = 0;
  u64 dgA = 0, dgB = 0;
  if (t < 256) {
    const int e0f = extS[0];
    if (1 + wsub <= e0f) {
      const u64* cbp = maskT + (size_t)(1 + wsub) * NBOX + sub * 8;
      mA0 = cbp[0]; mA1 = cbp[1]; mA2 = cbp[2]; mA3 = cbp[3];
      mA4 = cbp[4]; mA5 = cbp[5]; mA6 = cbp[6]; mA7 = cbp[7];
    }
    dgA = maskT[lane];
  }
  asm volatile("s_waitcnt lgkmcnt(0)" ::: "memory");
  __builtin_amdgcn_s_barrier();
  asm volatile("" ::: "memory");

  for (int c = 0; c < NWORDS; c += 2) {
    NSTEPF(c,     mA, dgA, mB, dgB);
    NSTEPF(c + 1, mB, dgB, mA, dgA);
  }
  if (t < NWORDS) aliveOut[t] = alvS[t];
}

// ---------------- Kernel 5: masked output ----------------
__global__ __launch_bounds__(256) void write_output(
    const float* __restrict__ boxes, const u64* __restrict__ alive,
    float* __restrict__ out)
{
  const int i = blockIdx.x * 256 + threadIdx.x;
  if (i < NBOX) {
    const bool k = (alive[i >> 6] >> (i & 63)) & 1ull;
    const float4 b = *(const float4*)&boxes[i * 4];
    const float4 z = {0.f, 0.f, 0.f, 0.f};
    *(float4*)&out[i * 4] = k ? b : z;
  }
}

extern "C" void kernel_launch(void* const* d_in, const int* in_sizes, int n_in,
                              void* d_out, int out_size, void* d_ws, size_t ws_size,
                              hipStream_t stream) {
  const float* X    = (const float*)d_in[0];  // (1,64,64,1024)
  const float* Wc   = (const float*)d_in[1];  // (3,3,1024,512)
  const float* Bc   = (const float*)d_in[2];  // (512,)
  const float* Wcls = (const float*)d_in[3];  // (1,1,512,6)
  const float* bcls = (const float*)d_in[4];  // (6,)
  const float* Wreg = (const float*)d_in[5];  // (1,1,512,12)
  const float* breg = (const float*)d_in[6];  // (12,)

  char* ws = (char*)d_ws;
  const size_t NEED_BIG = 52676864ull;   // Y4(33.55M)+misc+WT/maskT(18.87M)

  if (ws_size >= NEED_BIG) {
    // ---- partial-plane layout: no atomics, no zero_y ----
    float*     Y4     = (float*)    (ws);                  // 33,554,432 B (4 planes)
    float*     boxes  = (float*)    (ws + 33554432);       //    196,608 B
    float*     scores = (float*)    (ws + 33751040);       //     49,152 B
    u64*       aliveG = (u64*)      (ws + 33800192);       //      1,536 B
    int*       extG   = (int*)      (ws + 33801728);       //        768 B
    _Float16*  WTh    = (_Float16*) (ws + 33802496);       //  9,437,184 B
    _Float16*  WTl    = (_Float16*) (ws + 43239680);       //  9,437,184 B
    u64*       maskT  = (u64*)      (ws + 33802496);       // 18,874,368 B (post-conv reuse)

    prep_wt     <<<1152, 256, 0, stream>>>(Wc, WTh, WTl);
    conv_mfma   <<<512, 256, 0, stream>>>(X, WTh, WTl, Y4, 1);
    heads_decode<<<4096, 64, 0, stream>>>(Y4, 4, Bc, Wcls, bcls, Wreg, breg, boxes, scores, extG);
    build_mask  <<<dim3(192, 192), 256, 0, stream>>>(boxes, maskT, extG);
    nms_scan    <<<1, 1024, 0, stream>>>(scores, maskT, extG, aliveG);
    write_output<<<48, 256, 0, stream>>>(boxes, aliveG, (float*)d_out);
  } else {
    // ---- legacy layout: single Y, zero_y + atomicAdd ----
    float*     Y      = (float*)    (ws);                 // 8,388,608 B
    float*     boxes  = (float*)    (ws + 8388608);       //   196,608 B
    float*     scores = (float*)    (ws + 8585216);       //    49,152 B
    u64*       aliveG = (u64*)      (ws + 8634368);       //     1,536 B
    int*       extG   = (int*)      (ws + 8635904);       //       768 B
    _Float16*  WTh    = (_Float16*) (ws + 8636672);       // 9,437,184 B
    _Float16*  WTl    = (_Float16*) (ws + 18073856);      // 9,437,184 B
    u64*       maskT  = (u64*)      (ws + 8636672);       // 18,874,368 B (post-conv)

    zero_y      <<<2048, 256, 0, stream>>>((float4*)Y);
    prep_wt     <<<1152, 256, 0, stream>>>(Wc, WTh, WTl);
    conv_mfma   <<<512, 256, 0, stream>>>(X, WTh, WTl, Y, 0);
    heads_decode<<<4096, 64, 0, stream>>>(Y, 1, Bc, Wcls, bcls, Wreg, breg, boxes, scores, extG);
    build_mask  <<<dim3(192, 192), 256, 0, stream>>>(boxes, maskT, extG);
    nms_scan    <<<1, 1024, 0, stream>>>(scores, maskT, extG, aliveG);
    write_output<<<48, 256, 0, stream>>>(boxes, aliveG, (float*)d_out);
  }
}